// Round 1
// baseline (192.851 us; speedup 1.0000x reference)
//
#include <hip/hip_runtime.h>
#include <hip/hip_bf16.h>

// bior3.5 DWT, J=3 levels, zero-padding mode.
// Each level: out_lo[t] = sum_l h0[l]*x[2t+l-10], out_hi[t] = sum_l h1[l]*x[2t+l-10]
// with h1[i] = hac[11-i] * (i even ? -1 : +1), x zero-extended outside [0,N).

#define FILT_LEN 12
#define HALF_PAD 10

__global__ __launch_bounds__(256) void dwt_level_kernel(
    const float* __restrict__ x, const float* __restrict__ hac,
    float* __restrict__ lo, float* __restrict__ hi,
    int N, int outsize)
{
    const int t   = blockIdx.x * blockDim.x + threadIdx.x;
    const int row = blockIdx.y;
    if (t >= outsize) return;

    // Broadcast loads of the 12 filter taps (wave-uniform, L1-cached).
    float h0[FILT_LEN], h1[FILT_LEN];
#pragma unroll
    for (int i = 0; i < FILT_LEN; ++i) {
        float v = hac[i];
        h0[i] = v;
    }
#pragma unroll
    for (int i = 0; i < FILT_LEN; ++i) {
        h1[i] = h0[FILT_LEN - 1 - i] * ((i & 1) ? 1.0f : -1.0f);
    }

    const float* xr = x + (size_t)row * (size_t)N;
    const int base = 2 * t - HALF_PAD;

    float acc0 = 0.0f, acc1 = 0.0f;
#pragma unroll
    for (int l = 0; l < FILT_LEN; ++l) {
        const int j = base + l;
        float v = (j >= 0 && j < N) ? xr[j] : 0.0f;
        acc0 = fmaf(v, h0[l], acc0);
        acc1 = fmaf(v, h1[l], acc1);
    }

    lo[(size_t)row * (size_t)outsize + t] = acc0;
    hi[(size_t)row * (size_t)outsize + t] = acc1;
}

extern "C" void kernel_launch(void* const* d_in, const int* in_sizes, int n_in,
                              void* d_out, int out_size, void* d_ws, size_t ws_size,
                              hipStream_t stream)
{
    const float* x   = (const float*)d_in[0];
    const float* hac = (const float*)d_in[1];
    float* out = (float*)d_out;

    const int ROWS = 16 * 64;        // 1024 (B*C folded)
    const int N1 = 16384;
    const int O1 = 8197;             // (16384+11)/2
    const int O2 = 4104;             // (8197+11)/2
    const int O3 = 2057;             // (4104+11)/2

    // Workspace: lo1, lo2
    float* lo1 = (float*)d_ws;
    float* lo2 = lo1 + (size_t)ROWS * O1;

    // Output layout: (x0=lo3, hi1, hi2, hi3) concatenated flat
    float* x0  = out;
    float* hi1 = out + (size_t)ROWS * O3;
    float* hi2 = hi1 + (size_t)ROWS * O1;
    float* hi3 = hi2 + (size_t)ROWS * O2;

    const dim3 blk(256, 1, 1);

    dwt_level_kernel<<<dim3((O1 + 255) / 256, ROWS), blk, 0, stream>>>(
        x, hac, lo1, hi1, N1, O1);
    dwt_level_kernel<<<dim3((O2 + 255) / 256, ROWS), blk, 0, stream>>>(
        lo1, hac, lo2, hi2, O1, O2);
    dwt_level_kernel<<<dim3((O3 + 255) / 256, ROWS), blk, 0, stream>>>(
        lo2, hac, x0, hi3, O2, O3);
}

// Round 2
// 146.702 us; speedup vs baseline: 1.3146x; 1.3146x over previous
//
#include <hip/hip_runtime.h>
#include <hip/hip_bf16.h>

// Fully-fused bior3.5 DWT, J=3 levels, zero-padding mode.
// out_lo[t] = sum_l h0[l]*x[2t-10+l], out_hi[t] = sum_l h1[l]*x[2t-10+l],
// h1[i] = hac[11-i] * (i even ? -1 : +1), x zero-extended outside [0,N).
// lo1/lo2 never touch HBM: each block stages an x-chunk (+halo) in LDS,
// computes level-1 lo into LDS (halo recomputed redundantly across blocks),
// then level-2, then level-3. Only hi1/hi2/hi3/lo3 are written to global.

#define FILT_LEN 12
#define ROWS  1024
#define N1    16384
#define O1    8197
#define O2    4104
#define O3    2057
#define NBLK  4        // tiles per row
#define T1    2050     // ceil(O1/NBLK)
#define T2    1026
#define T3    515
#define NTHR  256

// LDS capacity (elements), sized to worst-case spans computed below:
// span1 max = 2090, xspan max = 2*2090+10 = 4190, span2 max = 1040
#define XCAP   4224
#define L1CAP  2112
#define L2CAP  1056

__global__ __launch_bounds__(NTHR) void dwt_fused_kernel(
    const float* __restrict__ x, const float* __restrict__ hac,
    float* __restrict__ lo3, float* __restrict__ hi1,
    float* __restrict__ hi2, float* __restrict__ hi3)
{
    __shared__ float xs_lds[XCAP];
    __shared__ float lo1_lds[L1CAP];
    __shared__ float lo2_lds[L2CAP];

    const int b   = blockIdx.x;   // tile within row
    const int row = blockIdx.y;
    const int tid = threadIdx.x;

    // Filter taps (wave-uniform broadcast loads)
    float h0[FILT_LEN], h1[FILT_LEN];
#pragma unroll
    for (int i = 0; i < FILT_LEN; ++i) h0[i] = hac[i];
#pragma unroll
    for (int i = 0; i < FILT_LEN; ++i)
        h1[i] = h0[FILT_LEN - 1 - i] * ((i & 1) ? 1.0f : -1.0f);

    // Own output partitions per level
    const int s1 = b * T1, e1 = min(s1 + T1, O1);
    const int s2 = b * T2, e2 = min(s2 + T2, O2);
    const int s3 = b * T3, e3 = min(s3 + T3, O3);

    // Compute ranges with halo (clamped to valid coefficient indices).
    // Level-3 outputs [s3,e3) read lo2[2t-10+l] -> g in [2*s3-10, 2*e3)
    const int c2s = max(0, min(s2, 2 * s3 - 10));
    const int c2e = min(O2, max(e2, 2 * e3));
    // Level-2 compute over [c2s,c2e) reads lo1 g in [2*c2s-10, 2*c2e)
    const int c1s = max(0, min(s1, 2 * c2s - 10));
    const int c1e = min(O1, max(e1, 2 * c2e));
    // Level-1 compute over [c1s,c1e) reads x j in [2*c1s-10, 2*c1e)
    const int xs = 2 * c1s - 10;            // may be negative (b==0)
    const int xe = 2 * c1e;                 // may exceed N1 (b==NBLK-1)
    const int xspan = xe - xs;
    const int span1 = c1e - c1s;
    const int span2 = c2e - c2s;

    const float* xrow = x + (size_t)row * N1;

    // ---- Stage x chunk into LDS (dense, coalesced, zero-extended) ----
    for (int i = tid; i < xspan; i += NTHR) {
        const int g = xs + i;
        xs_lds[i] = (g >= 0 && g < N1) ? xrow[g] : 0.0f;
    }
    __syncthreads();

    // ---- Level 1: compute lo1 (LDS) over [c1s,c1e), write hi1 for own range ----
    for (int tt = tid; tt < span1; tt += NTHR) {
        const int t = c1s + tt;
        float a0 = 0.0f, a1 = 0.0f;
        // x index j = 2t-10+l; LDS index = j - xs = 2*tt + l  (always in range)
#pragma unroll
        for (int l = 0; l < FILT_LEN; ++l) {
            const float v = xs_lds[2 * tt + l];
            a0 = fmaf(v, h0[l], a0);
            a1 = fmaf(v, h1[l], a1);
        }
        lo1_lds[tt] = a0;
        if (t >= s1 && t < e1) hi1[(size_t)row * O1 + t] = a1;
    }
    __syncthreads();

    // ---- Level 2: compute lo2 (LDS) over [c2s,c2e), write hi2 for own range ----
    for (int tt = tid; tt < span2; tt += NTHR) {
        const int t = c2s + tt;
        float a0 = 0.0f, a1 = 0.0f;
#pragma unroll
        for (int l = 0; l < FILT_LEN; ++l) {
            const int g = 2 * t - 10 + l;   // lo1 coefficient index
            const float v = (g >= 0 && g < O1) ? lo1_lds[g - c1s] : 0.0f;
            a0 = fmaf(v, h0[l], a0);
            a1 = fmaf(v, h1[l], a1);
        }
        lo2_lds[tt] = a0;
        if (t >= s2 && t < e2) hi2[(size_t)row * O2 + t] = a1;
    }
    __syncthreads();

    // ---- Level 3: compute lo3 + hi3 for own range only, write both ----
    for (int t = s3 + tid; t < e3; t += NTHR) {
        float a0 = 0.0f, a1 = 0.0f;
#pragma unroll
        for (int l = 0; l < FILT_LEN; ++l) {
            const int g = 2 * t - 10 + l;   // lo2 coefficient index
            const float v = (g >= 0 && g < O2) ? lo2_lds[g - c2s] : 0.0f;
            a0 = fmaf(v, h0[l], a0);
            a1 = fmaf(v, h1[l], a1);
        }
        lo3[(size_t)row * O3 + t] = a0;
        hi3[(size_t)row * O3 + t] = a1;
    }
}

extern "C" void kernel_launch(void* const* d_in, const int* in_sizes, int n_in,
                              void* d_out, int out_size, void* d_ws, size_t ws_size,
                              hipStream_t stream)
{
    const float* x   = (const float*)d_in[0];
    const float* hac = (const float*)d_in[1];
    float* out = (float*)d_out;

    // Output layout: (lo3, hi1, hi2, hi3) concatenated flat
    float* lo3 = out;
    float* hi1 = out + (size_t)ROWS * O3;
    float* hi2 = hi1 + (size_t)ROWS * O1;
    float* hi3 = hi2 + (size_t)ROWS * O2;

    dwt_fused_kernel<<<dim3(NBLK, ROWS), dim3(NTHR), 0, stream>>>(
        x, hac, lo3, hi1, hi2, hi3);
}

// Round 3
// 135.223 us; speedup vs baseline: 1.4262x; 1.0849x over previous
//
#include <hip/hip_runtime.h>

// Fully-fused bior3.5 DWT, J=3, zero-padding. Register-blocked + b128 LDS.
// Per block: stage x chunk (+halo) in LDS; L1: each thread computes 8
// consecutive output pairs from a 28-float register window (7 ds_read_b128);
// lo1 -> LDS, hi1 kept in regs then staged into the freed x region and
// flushed with stride-1 coalesced stores. Same scheme at L2 (4 outputs) and
// L3 (2 outputs). Filter taps are compile-time constants (fixed by setup).

#define FILT_LEN 12
#define ROWS  1024
#define N1    16384
#define O1    8197
#define O2    4104
#define O3    2057
#define NBLK  4
#define T1    2050
#define T2    1026
#define T3    515
#define NTHR  256

// LDS capacities (floats). span1<=2090, span2<=1040, span3<=515.
#define XCAP   4288
#define L1CAP  2128
#define L2CAP  1072
// staging regions inside xs_lds (valid after L1 reads complete)
#define HB1_OFF   0      // hi1: span1 <= 2090  (< 2112)
#define HB2_OFF   2112   // hi2: span2 <= 1040  (ends 3152 < 3168)
#define HB3LO_OFF 3168   // lo3: span3 <= 515   (ends 3683 < 3696)
#define HB3HI_OFF 3696   // hi3: span3 <= 515   (ends 4211 <= 4288)

// bior3.5 dec_lo (symmetric); h1[i] = h0[11-i] * (i odd ? +1 : -1)
__device__ __constant__ const float H0C[FILT_LEN] = {
    -0.013810679320049757f, 0.04143203796014927f, 0.052480581416189075f,
    -0.26792717880896527f, -0.07181553246425873f, 0.966747552403483f,
    0.966747552403483f, -0.07181553246425873f, -0.26792717880896527f,
    0.052480581416189075f, 0.04143203796014927f, -0.013810679320049757f};

__global__ __launch_bounds__(NTHR, 4) void dwt_fused_kernel(
    const float* __restrict__ x,
    float* __restrict__ lo3, float* __restrict__ hi1,
    float* __restrict__ hi2, float* __restrict__ hi3)
{
    __shared__ __align__(16) float xs_lds[XCAP];
    __shared__ __align__(16) float lo1_lds[L1CAP];
    __shared__ __align__(16) float lo2_lds[L2CAP];

    const int b   = blockIdx.x;
    const int row = blockIdx.y;
    const int tid = threadIdx.x;

    float h0[FILT_LEN], h1[FILT_LEN];
#pragma unroll
    for (int i = 0; i < FILT_LEN; ++i) h0[i] = H0C[i];
#pragma unroll
    for (int i = 0; i < FILT_LEN; ++i)
        h1[i] = h0[FILT_LEN - 1 - i] * ((i & 1) ? 1.0f : -1.0f);

    // --- ranges ---
    const int s1 = b * T1, e1 = min(s1 + T1, O1);
    const int s2 = b * T2, e2 = min(s2 + T2, O2);
    const int s3 = b * T3, e3 = min(s3 + T3, O3);
    const int c2s = max(0, min(s2, 2 * s3 - 10));
    const int c2e = min(O2, max(e2, 2 * e3));
    const int c1s = max(0, min(s1, 2 * c2s - 10)) & ~1;   // even
    const int c1e = min(O1, max(e1, 2 * c2e));
    const int span1 = c1e - c1s;
    const int span2 = c2e - c2s;
    const int span3 = e3 - s3;
    const int xbase = 2 * c1s - 12;                       // mult of 4

    // lo1_lds[g - c1s + PAD1]; choose PAD1 so DELTA2 = 2*c2s-10-c1s+PAD1 ≡ 0 mod 4
    const int d2raw = 2 * c2s - 10 - c1s + 12;            // even
    const int PAD1  = 12 + (d2raw & 2);
    const int DELTA2 = d2raw + (d2raw & 2);               // mult of 4
    const int d3raw = 2 * s3 - 10 - c2s + 12;             // even
    const int PAD2  = 12 + (d3raw & 2);
    const int DELTA3 = d3raw + (d3raw & 2);               // mult of 4

    const float* xrow = x + (size_t)row * N1;

    // ---------- Phase 1: zero lo1/lo2, stage x ----------
    {
        const float4 z4 = make_float4(0.f, 0.f, 0.f, 0.f);
        float4* l1p = reinterpret_cast<float4*>(lo1_lds);
        float4* l2p = reinterpret_cast<float4*>(lo2_lds);
#pragma unroll 2
        for (int i = tid; i < (L1CAP + L2CAP) / 4; i += NTHR) {
            if (i < L1CAP / 4) l1p[i] = z4;
            else               l2p[i - L1CAP / 4] = z4;
        }
        float4* xp = reinterpret_cast<float4*>(xs_lds);
        for (int i = tid; i < XCAP / 4; i += NTHR) {
            const int g0 = xbase + 4 * i;
            float4 v;
            if (g0 >= 0 && g0 + 4 <= N1) {
                v = *reinterpret_cast<const float4*>(&xrow[g0]);
            } else {
                v.x = (g0 + 0 >= 0 && g0 + 0 < N1) ? xrow[g0 + 0] : 0.f;
                v.y = (g0 + 1 >= 0 && g0 + 1 < N1) ? xrow[g0 + 1] : 0.f;
                v.z = (g0 + 2 >= 0 && g0 + 2 < N1) ? xrow[g0 + 2] : 0.f;
                v.w = (g0 + 3 >= 0 && g0 + 3 < N1) ? xrow[g0 + 3] : 0.f;
            }
            xp[i] = v;
        }
    }
    __syncthreads();

    // ---------- Phase 2: Level 1 (8 outputs/thread) ----------
    float hr1[2][8];
#pragma unroll
    for (int r = 0; r < 2; ++r) {
        const int tt0 = tid * 8 + r * 2048;
        if (tt0 < span1) {
            float w[28];
            const float4* wp = reinterpret_cast<const float4*>(&xs_lds[2 * tt0]);
#pragma unroll
            for (int m = 0; m < 7; ++m) {
                const float4 v = wp[m];
                w[4 * m + 0] = v.x; w[4 * m + 1] = v.y;
                w[4 * m + 2] = v.z; w[4 * m + 3] = v.w;
            }
            float a0[8], a1[8];
#pragma unroll
            for (int k = 0; k < 8; ++k) { a0[k] = 0.f; a1[k] = 0.f; }
#pragma unroll
            for (int l = 0; l < FILT_LEN; ++l) {
#pragma unroll
                for (int k = 0; k < 8; ++k) {
                    const float v = w[2 * k + 2 + l];
                    a0[k] = fmaf(v, h0[l], a0[k]);
                    a1[k] = fmaf(v, h1[l], a1[k]);
                }
            }
            if (tt0 + 8 <= span1) {
#pragma unroll
                for (int k = 0; k < 8; ++k) lo1_lds[tt0 + k + PAD1] = a0[k];
            } else {
#pragma unroll
                for (int k = 0; k < 8; ++k)
                    if (tt0 + k < span1) lo1_lds[tt0 + k + PAD1] = a0[k];
            }
#pragma unroll
            for (int k = 0; k < 8; ++k) hr1[r][k] = a1[k];
        }
    }
    __syncthreads();

    // ---------- Phase 3: stash hi1 into xs region; Level 2 (4 outputs/thread) ----------
#pragma unroll
    for (int r = 0; r < 2; ++r) {
        const int tt0 = tid * 8 + r * 2048;
        if (tt0 < span1) {
            if (tt0 + 8 <= span1) {
                float4* hp = reinterpret_cast<float4*>(&xs_lds[HB1_OFF + tt0]);
                hp[0] = make_float4(hr1[r][0], hr1[r][1], hr1[r][2], hr1[r][3]);
                hp[1] = make_float4(hr1[r][4], hr1[r][5], hr1[r][6], hr1[r][7]);
            } else {
#pragma unroll
                for (int k = 0; k < 8; ++k)
                    if (tt0 + k < span1) xs_lds[HB1_OFF + tt0 + k] = hr1[r][k];
            }
        }
    }
    float hr2[2][4];
#pragma unroll
    for (int r = 0; r < 2; ++r) {
        const int tt0 = tid * 4 + r * 1024;
        if (tt0 < span2) {
            float w[20];
            const float4* wp = reinterpret_cast<const float4*>(&lo1_lds[2 * tt0 + DELTA2]);
#pragma unroll
            for (int m = 0; m < 5; ++m) {
                const float4 v = wp[m];
                w[4 * m + 0] = v.x; w[4 * m + 1] = v.y;
                w[4 * m + 2] = v.z; w[4 * m + 3] = v.w;
            }
            float a0[4], a1[4];
#pragma unroll
            for (int k = 0; k < 4; ++k) { a0[k] = 0.f; a1[k] = 0.f; }
#pragma unroll
            for (int l = 0; l < FILT_LEN; ++l) {
#pragma unroll
                for (int k = 0; k < 4; ++k) {
                    const float v = w[2 * k + l];
                    a0[k] = fmaf(v, h0[l], a0[k]);
                    a1[k] = fmaf(v, h1[l], a1[k]);
                }
            }
#pragma unroll
            for (int k = 0; k < 4; ++k)
                if (tt0 + k < span2) lo2_lds[tt0 + k + PAD2] = a0[k];
#pragma unroll
            for (int k = 0; k < 4; ++k) hr2[r][k] = a1[k];
        }
    }
    __syncthreads();

    // ---------- Phase 4: flush hi1; stash hi2; Level 3 (2 outputs/thread) ----------
    {
        float* dst = hi1 + (size_t)row * O1;
        const int i0 = s1 - c1s, ie = e1 - c1s;
        for (int i = i0 + tid; i < ie; i += NTHR)
            dst[c1s + i] = xs_lds[HB1_OFF + i];
    }
#pragma unroll
    for (int r = 0; r < 2; ++r) {
        const int tt0 = tid * 4 + r * 1024;
        if (tt0 < span2) {
            if (tt0 + 4 <= span2) {
                *reinterpret_cast<float4*>(&xs_lds[HB2_OFF + tt0]) =
                    make_float4(hr2[r][0], hr2[r][1], hr2[r][2], hr2[r][3]);
            } else {
#pragma unroll
                for (int k = 0; k < 4; ++k)
                    if (tt0 + k < span2) xs_lds[HB2_OFF + tt0 + k] = hr2[r][k];
            }
        }
    }
#pragma unroll
    for (int r = 0; r < 2; ++r) {
        const int tt0 = tid * 2 + r * 512;
        if (tt0 < span3) {
            float w[16];
            const float4* wp = reinterpret_cast<const float4*>(&lo2_lds[2 * tt0 + DELTA3]);
#pragma unroll
            for (int m = 0; m < 4; ++m) {
                const float4 v = wp[m];
                w[4 * m + 0] = v.x; w[4 * m + 1] = v.y;
                w[4 * m + 2] = v.z; w[4 * m + 3] = v.w;
            }
            float a0[2], a1[2];
#pragma unroll
            for (int k = 0; k < 2; ++k) { a0[k] = 0.f; a1[k] = 0.f; }
#pragma unroll
            for (int l = 0; l < FILT_LEN; ++l) {
#pragma unroll
                for (int k = 0; k < 2; ++k) {
                    const float v = w[2 * k + l];
                    a0[k] = fmaf(v, h0[l], a0[k]);
                    a1[k] = fmaf(v, h1[l], a1[k]);
                }
            }
#pragma unroll
            for (int k = 0; k < 2; ++k) {
                if (tt0 + k < span3) {
                    xs_lds[HB3LO_OFF + tt0 + k] = a0[k];
                    xs_lds[HB3HI_OFF + tt0 + k] = a1[k];
                }
            }
        }
    }
    __syncthreads();

    // ---------- Phase 5: flush hi2, lo3, hi3 (coalesced) ----------
    {
        float* dst = hi2 + (size_t)row * O2;
        const int i0 = s2 - c2s, ie = e2 - c2s;
        for (int i = i0 + tid; i < ie; i += NTHR)
            dst[c2s + i] = xs_lds[HB2_OFF + i];
    }
    {
        float* dlo = lo3 + (size_t)row * O3 + s3;
        float* dhi = hi3 + (size_t)row * O3 + s3;
        for (int i = tid; i < span3; i += NTHR) {
            dlo[i] = xs_lds[HB3LO_OFF + i];
            dhi[i] = xs_lds[HB3HI_OFF + i];
        }
    }
}

extern "C" void kernel_launch(void* const* d_in, const int* in_sizes, int n_in,
                              void* d_out, int out_size, void* d_ws, size_t ws_size,
                              hipStream_t stream)
{
    const float* x = (const float*)d_in[0];
    float* out = (float*)d_out;

    // Output layout: (lo3, hi1, hi2, hi3) concatenated flat
    float* lo3 = out;
    float* hi1 = out + (size_t)ROWS * O3;
    float* hi2 = hi1 + (size_t)ROWS * O1;
    float* hi3 = hi2 + (size_t)ROWS * O2;

    dwt_fused_kernel<<<dim3(NBLK, ROWS), dim3(NTHR), 0, stream>>>(
        x, lo3, hi1, hi2, hi3);
}

// Round 5
// 120.165 us; speedup vs baseline: 1.6049x; 1.1253x over previous
//
#include <hip/hip_runtime.h>

// Fully-fused bior3.5 DWT, J=3, zero-padding. Register-blocked, XOR-swizzled
// LDS, compile-time per-block-tile constants (templated on tile index B).
//
// LDS plan (25.6 KB -> 6 blocks/CU):
//   xs[4288]:  P1-P2: staged x (+halo).  P3+: hi1 stash [0,span1),
//              lo2 coeffs [2112,3168), hi2 stash [3200,3200+span2).
//   l1[2112]:  P2-P3: lo1 coeffs (PAD 12).  P4+: lo3 stash [0,515),
//              hi3 stash [544,544+515).
// All LDS accesses go through an XOR swizzle on the float4 index so the
// lane-stride-16/8-float b128 window reads are bank-conflict-minimal.

#define FILT_LEN 12
#define ROWS  1024
#define N1    16384
#define O1    8197
#define O2    4104
#define O3    2057
#define NBLK  4
#define T1    2050
#define T2    1026
#define T3    515
#define NTHR  256

#define XCAP   4288      // floats
#define L1CAP  2112      // floats
#define LO2_OFF  2112    // lo2 (incl PAD2=12): [2112, 3168)
#define HB2_OFF  3200    // hi2 stash: [3200, 4240)
#define LO3_OFF  0       // in l1
#define HI3_OFF  544     // in l1

constexpr int cmin(int a, int b) { return a < b ? a : b; }
constexpr int cmax(int a, int b) { return a > b ? a : b; }

__device__ __forceinline__ int sw4(int f4) { return f4 ^ ((f4 >> 3) & 7); }
__device__ __forceinline__ float4 ld4(const float* p, int f4) {
    return reinterpret_cast<const float4*>(p)[sw4(f4)];
}
__device__ __forceinline__ void st4(float* p, int f4, float4 v) {
    reinterpret_cast<float4*>(p)[sw4(f4)] = v;
}
__device__ __forceinline__ float ldss(const float* p, int j) {
    return p[(sw4(j >> 2) << 2) | (j & 3)];
}
__device__ __forceinline__ void stss(float* p, int j, float v) {
    p[(sw4(j >> 2) << 2) | (j & 3)] = v;
}

__device__ __forceinline__ float h0tap(int i) {
    constexpr float H[FILT_LEN] = {
        -0.013810679320049757f, 0.04143203796014927f, 0.052480581416189075f,
        -0.26792717880896527f, -0.07181553246425873f, 0.966747552403483f,
        0.966747552403483f, -0.07181553246425873f, -0.26792717880896527f,
        0.052480581416189075f, 0.04143203796014927f, -0.013810679320049757f};
    return H[i];
}

template<int B>
struct Cfg {
    static constexpr int s1 = B * T1, e1 = cmin(s1 + T1, O1);
    static constexpr int s2 = B * T2, e2 = cmin(s2 + T2, O2);
    static constexpr int s3 = B * T3, e3 = cmin(s3 + T3, O3);
    static constexpr int c2s = cmax(0, cmin(s2, 2 * s3 - 10));
    static constexpr int c2e = cmin(O2, cmax(e2, 2 * e3));
    static constexpr int c1s = cmax(0, cmin(s1, 2 * c2s - 10)) & ~1;  // even
    static constexpr int c1e = cmin(O1, cmax(e1, 2 * c2e));
    static constexpr int span1 = c1e - c1s;     // <= 2090
    static constexpr int span2 = c2e - c2s;     // <= 1040
    static constexpr int span3 = e3 - s3;       // <= 515
    static constexpr int xbase = 2 * c1s - 12;  // mult of 4
    // lo1 logical window start for L2 output tt: 2*tt + D2 + l
    static constexpr int D2 = 2 * c2s - 10 - c1s + 12;   // >= 0, even
    static constexpr int ab2 = D2 & ~3, p2 = D2 & 3;     // p2 in {0,2}
    // lo2 logical window start for L3 output tt: 2*tt + D3 + l
    static constexpr int D3 = 2 * s3 - 10 - c2s + 12;    // >= 0, even
    static constexpr int ab3 = D3 & ~3, p3 = D3 & 3;     // p3 in {0,2}
    static constexpr int zt1 = 2104 - (12 + span1);      // l1 tail zeros
    static constexpr int zt2 = 1056 - (12 + span2);      // lo2 tail zeros
};

template<int B>
__device__ __forceinline__ void body(
    const float* __restrict__ xrow,
    float* __restrict__ lo3r, float* __restrict__ hi1r,
    float* __restrict__ hi2r, float* __restrict__ hi3r,
    float* __restrict__ xs, float* __restrict__ l1, const int tid)
{
    using C = Cfg<B>;

    float h0[FILT_LEN], h1[FILT_LEN];
#pragma unroll
    for (int i = 0; i < FILT_LEN; ++i) {
        h0[i] = h0tap(i);
        h1[i] = h0tap(FILT_LEN - 1 - i) * ((i & 1) ? 1.0f : -1.0f);
    }

    // ---------- P1: stage x (swizzled), zero l1 pads ----------
    if constexpr (C::xbase >= 0 && C::xbase + XCAP <= N1) {
        for (int i = tid; i < XCAP / 4; i += NTHR)
            st4(xs, i, *reinterpret_cast<const float4*>(xrow + C::xbase + 4 * i));
    } else {
        for (int i = tid; i < XCAP / 4; i += NTHR) {
            const int g0 = C::xbase + 4 * i;
            float4 v;
            if (g0 >= 0 && g0 + 4 <= N1) {
                v = *reinterpret_cast<const float4*>(xrow + g0);
            } else {
                v.x = ((unsigned)(g0 + 0) < (unsigned)N1) ? xrow[g0 + 0] : 0.f;
                v.y = ((unsigned)(g0 + 1) < (unsigned)N1) ? xrow[g0 + 1] : 0.f;
                v.z = ((unsigned)(g0 + 2) < (unsigned)N1) ? xrow[g0 + 2] : 0.f;
                v.w = ((unsigned)(g0 + 3) < (unsigned)N1) ? xrow[g0 + 3] : 0.f;
            }
            st4(xs, i, v);
        }
    }
    if (tid < 12)      stss(l1, tid, 0.f);
    if (tid < C::zt1)  stss(l1, 12 + C::span1 + tid, 0.f);
    __syncthreads();

    // ---------- P2: Level 1 (8 outputs/thread) ----------
    float hr1[2][8];
#pragma unroll
    for (int r = 0; r < 2; ++r) {
        const int tt0 = tid * 8 + r * 2048;
        if (tt0 < C::span1) {
            float w[28];
            // window logical float index = 2*tt0 = 16*tid + 4096*r
            // -> float4 index = 4*tid + 1024*r   (R3 bug: had r*512)
            const int f0 = tid * 4 + r * 1024;
#pragma unroll
            for (int m = 0; m < 7; ++m) {
                const float4 v = ld4(xs, f0 + m);
                w[4 * m + 0] = v.x; w[4 * m + 1] = v.y;
                w[4 * m + 2] = v.z; w[4 * m + 3] = v.w;
            }
            float a0[8], a1[8];
#pragma unroll
            for (int k = 0; k < 8; ++k) { a0[k] = 0.f; a1[k] = 0.f; }
#pragma unroll
            for (int l = 0; l < FILT_LEN; ++l) {
#pragma unroll
                for (int k = 0; k < 8; ++k) {
                    const float v = w[2 * k + 2 + l];
                    a0[k] = fmaf(v, h0[l], a0[k]);
                    a1[k] = fmaf(v, h1[l], a1[k]);
                }
            }
            // lo1 at logical 12+tt0 (f4 = 3 + 2*tid + 512r)
            if (tt0 + 8 <= C::span1) {
                st4(l1, 3 + tid * 2 + r * 512,
                    make_float4(a0[0], a0[1], a0[2], a0[3]));
                st4(l1, 4 + tid * 2 + r * 512,
                    make_float4(a0[4], a0[5], a0[6], a0[7]));
            } else {
#pragma unroll
                for (int k = 0; k < 8; ++k)
                    if (tt0 + k < C::span1) stss(l1, 12 + tt0 + k, a0[k]);
            }
#pragma unroll
            for (int k = 0; k < 8; ++k) hr1[r][k] = a1[k];
        }
    }
    __syncthreads();

    // ---------- P3: stash hi1 -> xs[0..span1); zero lo2 pads; Level 2 ----------
#pragma unroll
    for (int r = 0; r < 2; ++r) {
        const int tt0 = tid * 8 + r * 2048;
        if (tt0 < C::span1) {
            if (tt0 + 8 <= C::span1) {
                st4(xs, tid * 2 + r * 512,
                    make_float4(hr1[r][0], hr1[r][1], hr1[r][2], hr1[r][3]));
                st4(xs, tid * 2 + r * 512 + 1,
                    make_float4(hr1[r][4], hr1[r][5], hr1[r][6], hr1[r][7]));
            } else {
#pragma unroll
                for (int k = 0; k < 8; ++k)
                    if (tt0 + k < C::span1) stss(xs, tt0 + k, hr1[r][k]);
            }
        }
    }
    if (tid < 12)      stss(xs, LO2_OFF + tid, 0.f);
    if (tid < C::zt2)  stss(xs, LO2_OFF + 12 + C::span2 + tid, 0.f);

    float hr2[2][4];
#pragma unroll
    for (int r = 0; r < 2; ++r) {
        const int tt0 = tid * 4 + r * 1024;
        if (tt0 < C::span2) {
            float w[20];
            const int f0 = tid * 2 + r * 512 + (C::ab2 >> 2);  // (2*tt0+ab2)>>2
#pragma unroll
            for (int m = 0; m < 5; ++m) {
                const float4 v = ld4(l1, f0 + m);
                w[4 * m + 0] = v.x; w[4 * m + 1] = v.y;
                w[4 * m + 2] = v.z; w[4 * m + 3] = v.w;
            }
            float a0[4], a1[4];
#pragma unroll
            for (int k = 0; k < 4; ++k) { a0[k] = 0.f; a1[k] = 0.f; }
#pragma unroll
            for (int l = 0; l < FILT_LEN; ++l) {
#pragma unroll
                for (int k = 0; k < 4; ++k) {
                    const float v = w[2 * k + l + C::p2];
                    a0[k] = fmaf(v, h0[l], a0[k]);
                    a1[k] = fmaf(v, h1[l], a1[k]);
                }
            }
            // lo2 at logical LO2_OFF+12+tt0 (f4 = 531 + tid + 256r)
            if (tt0 + 4 <= C::span2) {
                st4(xs, 531 + tid + r * 256,
                    make_float4(a0[0], a0[1], a0[2], a0[3]));
            } else {
#pragma unroll
                for (int k = 0; k < 4; ++k)
                    if (tt0 + k < C::span2) stss(xs, LO2_OFF + 12 + tt0 + k, a0[k]);
            }
#pragma unroll
            for (int k = 0; k < 4; ++k) hr2[r][k] = a1[k];
        }
    }
    __syncthreads();

    // ---------- P4: flush hi1; stash hi2; Level 3 -> stash in l1 ----------
    for (int i = (C::s1 - C::c1s) + tid; i < C::e1 - C::c1s; i += NTHR)
        hi1r[C::c1s + i] = ldss(xs, i);

#pragma unroll
    for (int r = 0; r < 2; ++r) {
        const int tt0 = tid * 4 + r * 1024;
        if (tt0 < C::span2) {
            if (tt0 + 4 <= C::span2) {
                st4(xs, (HB2_OFF >> 2) + tid + r * 256,
                    make_float4(hr2[r][0], hr2[r][1], hr2[r][2], hr2[r][3]));
            } else {
#pragma unroll
                for (int k = 0; k < 4; ++k)
                    if (tt0 + k < C::span2) stss(xs, HB2_OFF + tt0 + k, hr2[r][k]);
            }
        }
    }

#pragma unroll
    for (int r = 0; r < 2; ++r) {
        const int tt0 = tid * 2 + r * 512;
        if (tt0 < C::span3) {
            float w[16];
            const int f0 = (LO2_OFF >> 2) + tid + r * 256 + (C::ab3 >> 2);
#pragma unroll
            for (int m = 0; m < 4; ++m) {
                const float4 v = ld4(xs, f0 + m);
                w[4 * m + 0] = v.x; w[4 * m + 1] = v.y;
                w[4 * m + 2] = v.z; w[4 * m + 3] = v.w;
            }
            float a0[2], a1[2];
#pragma unroll
            for (int k = 0; k < 2; ++k) { a0[k] = 0.f; a1[k] = 0.f; }
#pragma unroll
            for (int l = 0; l < FILT_LEN; ++l) {
#pragma unroll
                for (int k = 0; k < 2; ++k) {
                    const float v = w[2 * k + l + C::p3];
                    a0[k] = fmaf(v, h0[l], a0[k]);
                    a1[k] = fmaf(v, h1[l], a1[k]);
                }
            }
#pragma unroll
            for (int k = 0; k < 2; ++k) {
                if (tt0 + k < C::span3) {
                    stss(l1, LO3_OFF + tt0 + k, a0[k]);
                    stss(l1, HI3_OFF + tt0 + k, a1[k]);
                }
            }
        }
    }
    __syncthreads();

    // ---------- P5: flush hi2, lo3, hi3 ----------
    for (int i = (C::s2 - C::c2s) + tid; i < C::e2 - C::c2s; i += NTHR)
        hi2r[C::c2s + i] = ldss(xs, HB2_OFF + i);
    for (int i = tid; i < C::span3; i += NTHR) {
        lo3r[C::s3 + i] = ldss(l1, LO3_OFF + i);
        hi3r[C::s3 + i] = ldss(l1, HI3_OFF + i);
    }
}

__global__ __launch_bounds__(NTHR, 6) void dwt_fused_kernel(
    const float* __restrict__ x,
    float* __restrict__ lo3, float* __restrict__ hi1,
    float* __restrict__ hi2, float* __restrict__ hi3)
{
    __shared__ __align__(16) float xs[XCAP];
    __shared__ __align__(16) float l1[L1CAP];

    const int row = blockIdx.y;
    const int tid = threadIdx.x;
    const float* xrow = x + (size_t)row * N1;
    float* lo3r = lo3 + (size_t)row * O3;
    float* hi1r = hi1 + (size_t)row * O1;
    float* hi2r = hi2 + (size_t)row * O2;
    float* hi3r = hi3 + (size_t)row * O3;

    switch (blockIdx.x) {
        case 0:  body<0>(xrow, lo3r, hi1r, hi2r, hi3r, xs, l1, tid); break;
        case 1:  body<1>(xrow, lo3r, hi1r, hi2r, hi3r, xs, l1, tid); break;
        case 2:  body<2>(xrow, lo3r, hi1r, hi2r, hi3r, xs, l1, tid); break;
        default: body<3>(xrow, lo3r, hi1r, hi2r, hi3r, xs, l1, tid); break;
    }
}

extern "C" void kernel_launch(void* const* d_in, const int* in_sizes, int n_in,
                              void* d_out, int out_size, void* d_ws, size_t ws_size,
                              hipStream_t stream)
{
    const float* x = (const float*)d_in[0];
    float* out = (float*)d_out;

    // Output layout: (lo3, hi1, hi2, hi3) concatenated flat
    float* lo3 = out;
    float* hi1 = out + (size_t)ROWS * O3;
    float* hi2 = hi1 + (size_t)ROWS * O1;
    float* hi3 = hi2 + (size_t)ROWS * O2;

    dwt_fused_kernel<<<dim3(NBLK, ROWS), dim3(NTHR), 0, stream>>>(
        x, lo3, hi1, hi2, hi3);
}

// Round 7
// 118.845 us; speedup vs baseline: 1.6227x; 1.0111x over previous
//
#include <hip/hip_runtime.h>

// Fully-fused bior3.5 DWT, J=3, zero-padding. NBLK=8 tiles/row, 8 blocks/CU
// (100% wave occupancy), K=8 register blocking, XOR-swizzled LDS, 4 barriers.
//
// LDS (13.3 KB/block):
//   xs[2208]: P1-P2 staged x (+halo). P3+: hi1 stash [0,span1),
//             lo2 [1088,1648), hi2 stash [1664,1664+span2).
//   l1[1120]: P2-P3 lo1 coeffs (pad 12). P4+: lo3 [0,span3), hi3 [272,..).
//
// R5 bug fixed here: c2s must be forced EVEN (T2=513 is odd, so B*T2 can be
// odd), else D3 becomes odd and p3 can reach 3 -> L3 window overruns w[28].
// Parity static_asserts added so a retile fails to compile instead.

#define FILT_LEN 12
#define ROWS  1024
#define N1    16384
#define O1    8197
#define O2    4104
#define O3    2057
#define NBLK  8
#define T1    1025
#define T2    513
#define T3    258
#define NTHR  256

#define XCAP    2208     // floats (552 float4)
#define L1CAP   1120
#define LO2_OFF 1088     // in xs; region size LO2SZ
#define LO2SZ   560
#define HB2_OFF 1664     // in xs
#define HI3_OFF 272      // in l1

constexpr int cmin(int a, int b) { return a < b ? a : b; }
constexpr int cmax(int a, int b) { return a > b ? a : b; }

__device__ __forceinline__ int sw4(int f4) { return f4 ^ ((f4 >> 3) & 7); }
__device__ __forceinline__ float4 ld4(const float* p, int f4) {
    return reinterpret_cast<const float4*>(p)[sw4(f4)];
}
__device__ __forceinline__ void st4(float* p, int f4, float4 v) {
    reinterpret_cast<float4*>(p)[sw4(f4)] = v;
}
__device__ __forceinline__ float ldss(const float* p, int j) {
    return p[(sw4(j >> 2) << 2) | (j & 3)];
}
__device__ __forceinline__ void stss(float* p, int j, float v) {
    p[(sw4(j >> 2) << 2) | (j & 3)] = v;
}

__device__ __forceinline__ constexpr float h0tap(int i) {
    constexpr float H[FILT_LEN] = {
        -0.013810679320049757f, 0.04143203796014927f, 0.052480581416189075f,
        -0.26792717880896527f, -0.07181553246425873f, 0.966747552403483f,
        0.966747552403483f, -0.07181553246425873f, -0.26792717880896527f,
        0.052480581416189075f, 0.04143203796014927f, -0.013810679320049757f};
    return H[i];
}
__device__ __forceinline__ constexpr float h1tap(int i) {
    return h0tap(FILT_LEN - 1 - i) * ((i & 1) ? 1.0f : -1.0f);
}

template<int B>
struct Cfg {
    static constexpr int s1 = B * T1, e1 = cmin(s1 + T1, O1);
    static constexpr int s2 = B * T2, e2 = cmin(s2 + T2, O2);
    static constexpr int s3 = B * T3, e3 = cmin(s3 + T3, O3);
    static constexpr int c2s = cmax(0, cmin(s2, 2 * s3 - 10)) & ~1;  // even!
    static constexpr int c2e = cmin(O2, cmax(e2, 2 * e3));
    static constexpr int c1s = cmax(0, cmin(s1, 2 * c2s - 10)) & ~1;  // even
    static constexpr int c1e = cmin(O1, cmax(e1, 2 * c2e));
    static constexpr int span1 = c1e - c1s;     // <= 1078
    static constexpr int span2 = c2e - c2s;     // <= 534
    static constexpr int span3 = e3 - s3;       // <= 258
    static constexpr int xbase = 2 * c1s - 12;  // mult of 4
    static constexpr int D2 = 2 * c2s - 10 - c1s + 12;   // even, >=0
    static constexpr int ab2 = D2 & ~3, p2 = D2 & 3;     // p2 in {0,2}
    static constexpr int D3 = 2 * s3 - 10 - c2s + 12;    // even, >=0
    static constexpr int ab3 = D3 & ~3, p3 = D3 & 3;     // p3 in {0,2}
    static constexpr int zt1 = L1CAP - (12 + span1);
    static constexpr int zt2 = LO2SZ - (12 + span2);
    static constexpr int o1s = s1 - c1s, o1e = e1 - c1s;
    static constexpr int o2s = s2 - c2s, o2e = e2 - c2s;

    static_assert(D2 >= 0 && D3 >= 0, "pad origin");
    static_assert((D2 & 1) == 0 && (D3 & 1) == 0, "window parity (R5 bug)");
    static_assert(p2 <= 2 && p3 <= 2, "window shift fits 28-float window");
    static_assert((xbase & 3) == 0, "x staging alignment");
    static_assert(zt1 >= 0 && zt1 <= NTHR, "l1 tail zero in one pass");
    static_assert(zt2 >= 0 && zt2 <= NTHR, "lo2 tail zero in one pass");
    static_assert(span1 <= 8 * NTHR && span2 <= 8 * NTHR && span3 <= 8 * NTHR,
                  "single K=8 pass");
    static_assert(2 * (((span1 - 1) / 8) * 8) + 25 + 2 < XCAP, "L1 window read");
    static_assert(2 * (((span2 - 1) / 8) * 8) + ab2 + 25 + p2 < L1CAP, "L2 window read");
    static_assert(2 * (((span3 - 1) / 8) * 8) + ab3 + 25 + p3 < LO2SZ, "L3 window read");
    static_assert(span1 <= LO2_OFF, "hi1 stash fits");
    static_assert(HB2_OFF + span2 <= XCAP, "hi2 stash fits");
    static_assert(HI3_OFF + span3 <= L1CAP, "hi3 stash fits");
    static_assert(HI3_OFF >= span3, "lo3/hi3 disjoint");
};

template<int B>
__device__ __forceinline__ void body(
    const float* __restrict__ xrow,
    float* __restrict__ lo3r, float* __restrict__ hi1r,
    float* __restrict__ hi2r, float* __restrict__ hi3r,
    float* __restrict__ xs, float* __restrict__ l1, const int tid)
{
    using C = Cfg<B>;

    // ---------- P1: stage x (swizzled), zero l1 pads ----------
    if constexpr (C::xbase >= 0 && C::xbase + XCAP <= N1) {
        st4(xs, tid,       *reinterpret_cast<const float4*>(xrow + C::xbase + 4 * tid));
        st4(xs, tid + 256, *reinterpret_cast<const float4*>(xrow + C::xbase + 1024 + 4 * tid));
        if (tid < XCAP / 4 - 512)
            st4(xs, tid + 512, *reinterpret_cast<const float4*>(xrow + C::xbase + 2048 + 4 * tid));
    } else {
        for (int i = tid; i < XCAP / 4; i += NTHR) {
            const int g0 = C::xbase + 4 * i;
            float4 v;
            if (g0 >= 0 && g0 + 4 <= N1) {
                v = *reinterpret_cast<const float4*>(xrow + g0);
            } else {
                v.x = ((unsigned)(g0 + 0) < (unsigned)N1) ? xrow[g0 + 0] : 0.f;
                v.y = ((unsigned)(g0 + 1) < (unsigned)N1) ? xrow[g0 + 1] : 0.f;
                v.z = ((unsigned)(g0 + 2) < (unsigned)N1) ? xrow[g0 + 2] : 0.f;
                v.w = ((unsigned)(g0 + 3) < (unsigned)N1) ? xrow[g0 + 3] : 0.f;
            }
            st4(xs, i, v);
        }
    }
    if (tid < 12)      stss(l1, tid, 0.f);
    if (tid < C::zt1)  stss(l1, 12 + C::span1 + tid, 0.f);
    __syncthreads();

    // ---------- P2: Level 1, K=8 (single pass) ----------
    float hr1[8];
    const int tt1 = tid * 8;
    if (tt1 < C::span1) {
        float w[28];
#pragma unroll
        for (int m = 0; m < 7; ++m) {
            const float4 v = ld4(xs, tid * 4 + m);   // logical 2*tt1 = 16*tid
            w[4 * m + 0] = v.x; w[4 * m + 1] = v.y;
            w[4 * m + 2] = v.z; w[4 * m + 3] = v.w;
        }
        float a0[8];
#pragma unroll
        for (int k = 0; k < 8; ++k) { a0[k] = 0.f; hr1[k] = 0.f; }
#pragma unroll
        for (int l = 0; l < FILT_LEN; ++l) {
#pragma unroll
            for (int k = 0; k < 8; ++k) {
                const float v = w[2 * k + 2 + l];     // x idx 2t-10+l, window base 2t-12
                a0[k]  = fmaf(v, h0tap(l), a0[k]);
                hr1[k] = fmaf(v, h1tap(l), hr1[k]);
            }
        }
        if (tt1 + 8 <= C::span1) {                    // lo1 at logical 12+tt1
            st4(l1, 3 + 2 * tid, make_float4(a0[0], a0[1], a0[2], a0[3]));
            st4(l1, 4 + 2 * tid, make_float4(a0[4], a0[5], a0[6], a0[7]));
        } else {
#pragma unroll
            for (int k = 0; k < 8; ++k)
                if (tt1 + k < C::span1) stss(l1, 12 + tt1 + k, a0[k]);
        }
    }
    __syncthreads();

    // ---------- P3: stash hi1; zero lo2 pads; Level 2, K=8 ----------
    if (tt1 < C::span1) {
        if (tt1 + 8 <= C::span1) {
            st4(xs, 2 * tid,     make_float4(hr1[0], hr1[1], hr1[2], hr1[3]));
            st4(xs, 2 * tid + 1, make_float4(hr1[4], hr1[5], hr1[6], hr1[7]));
        } else {
#pragma unroll
            for (int k = 0; k < 8; ++k)
                if (tt1 + k < C::span1) stss(xs, tt1 + k, hr1[k]);
        }
    }
    if (tid < 12)      stss(xs, LO2_OFF + tid, 0.f);
    if (tid < C::zt2)  stss(xs, LO2_OFF + 12 + C::span2 + tid, 0.f);

    {
        const int tt2 = tid * 8;
        if (tt2 < C::span2) {
            float w[28];
#pragma unroll
            for (int m = 0; m < 7; ++m) {   // l1 logical 2*tt2+ab2 = 16*tid+ab2
                const float4 v = ld4(l1, tid * 4 + (C::ab2 >> 2) + m);
                w[4 * m + 0] = v.x; w[4 * m + 1] = v.y;
                w[4 * m + 2] = v.z; w[4 * m + 3] = v.w;
            }
            float a0[8], a1[8];
#pragma unroll
            for (int k = 0; k < 8; ++k) { a0[k] = 0.f; a1[k] = 0.f; }
#pragma unroll
            for (int l = 0; l < FILT_LEN; ++l) {
#pragma unroll
                for (int k = 0; k < 8; ++k) {
                    const float v = w[2 * k + l + C::p2];
                    a0[k] = fmaf(v, h0tap(l), a0[k]);
                    a1[k] = fmaf(v, h1tap(l), a1[k]);
                }
            }
            if (tt2 + 8 <= C::span2) {
                // lo2 at logical LO2_OFF+12+tt2 -> f4 = 275 + 2*tid
                st4(xs, 275 + 2 * tid, make_float4(a0[0], a0[1], a0[2], a0[3]));
                st4(xs, 276 + 2 * tid, make_float4(a0[4], a0[5], a0[6], a0[7]));
                // hi2 stash at HB2_OFF+tt2 -> f4 = 416 + 2*tid
                st4(xs, 416 + 2 * tid, make_float4(a1[0], a1[1], a1[2], a1[3]));
                st4(xs, 417 + 2 * tid, make_float4(a1[4], a1[5], a1[6], a1[7]));
            } else {
#pragma unroll
                for (int k = 0; k < 8; ++k) {
                    if (tt2 + k < C::span2) {
                        stss(xs, LO2_OFF + 12 + tt2 + k, a0[k]);
                        stss(xs, HB2_OFF + tt2 + k, a1[k]);
                    }
                }
            }
        }
    }
    __syncthreads();

    // ---------- P4: flush hi1+hi2; Level 3, K=8 -> stash in l1 ----------
    for (int i = C::o1s + tid; i < C::o1e; i += NTHR)
        hi1r[C::c1s + i] = ldss(xs, i);
    for (int i = C::o2s + tid; i < C::o2e; i += NTHR)
        hi2r[C::c2s + i] = ldss(xs, HB2_OFF + i);

    {
        const int tt3 = tid * 8;
        if (tt3 < C::span3) {
            float w[28];
#pragma unroll
            for (int m = 0; m < 7; ++m) {   // xs logical LO2_OFF+2*tt3+ab3
                const float4 v = ld4(xs, (LO2_OFF >> 2) + tid * 4 + (C::ab3 >> 2) + m);
                w[4 * m + 0] = v.x; w[4 * m + 1] = v.y;
                w[4 * m + 2] = v.z; w[4 * m + 3] = v.w;
            }
            float a0[8], a1[8];
#pragma unroll
            for (int k = 0; k < 8; ++k) { a0[k] = 0.f; a1[k] = 0.f; }
#pragma unroll
            for (int l = 0; l < FILT_LEN; ++l) {
#pragma unroll
                for (int k = 0; k < 8; ++k) {
                    const float v = w[2 * k + l + C::p3];
                    a0[k] = fmaf(v, h0tap(l), a0[k]);
                    a1[k] = fmaf(v, h1tap(l), a1[k]);
                }
            }
            if (tt3 + 8 <= C::span3) {
                st4(l1, 2 * tid,                     make_float4(a0[0], a0[1], a0[2], a0[3]));
                st4(l1, 2 * tid + 1,                 make_float4(a0[4], a0[5], a0[6], a0[7]));
                st4(l1, (HI3_OFF >> 2) + 2 * tid,     make_float4(a1[0], a1[1], a1[2], a1[3]));
                st4(l1, (HI3_OFF >> 2) + 2 * tid + 1, make_float4(a1[4], a1[5], a1[6], a1[7]));
            } else {
#pragma unroll
                for (int k = 0; k < 8; ++k) {
                    if (tt3 + k < C::span3) {
                        stss(l1, tt3 + k, a0[k]);
                        stss(l1, HI3_OFF + tt3 + k, a1[k]);
                    }
                }
            }
        }
    }
    __syncthreads();

    // ---------- P5: flush lo3, hi3 ----------
    for (int i = tid; i < C::span3; i += NTHR) {
        lo3r[C::s3 + i] = ldss(l1, i);
        hi3r[C::s3 + i] = ldss(l1, HI3_OFF + i);
    }
}

__global__ __launch_bounds__(NTHR, 8) void dwt_fused_kernel(
    const float* __restrict__ x,
    float* __restrict__ lo3, float* __restrict__ hi1,
    float* __restrict__ hi2, float* __restrict__ hi3)
{
    __shared__ __align__(16) float xs[XCAP];
    __shared__ __align__(16) float l1[L1CAP];

    const int row = blockIdx.y;
    const int tid = threadIdx.x;
    const float* xrow = x + (size_t)row * N1;
    float* lo3r = lo3 + (size_t)row * O3;
    float* hi1r = hi1 + (size_t)row * O1;
    float* hi2r = hi2 + (size_t)row * O2;
    float* hi3r = hi3 + (size_t)row * O3;

    switch (blockIdx.x) {
        case 0:  body<0>(xrow, lo3r, hi1r, hi2r, hi3r, xs, l1, tid); break;
        case 1:  body<1>(xrow, lo3r, hi1r, hi2r, hi3r, xs, l1, tid); break;
        case 2:  body<2>(xrow, lo3r, hi1r, hi2r, hi3r, xs, l1, tid); break;
        case 3:  body<3>(xrow, lo3r, hi1r, hi2r, hi3r, xs, l1, tid); break;
        case 4:  body<4>(xrow, lo3r, hi1r, hi2r, hi3r, xs, l1, tid); break;
        case 5:  body<5>(xrow, lo3r, hi1r, hi2r, hi3r, xs, l1, tid); break;
        case 6:  body<6>(xrow, lo3r, hi1r, hi2r, hi3r, xs, l1, tid); break;
        default: body<7>(xrow, lo3r, hi1r, hi2r, hi3r, xs, l1, tid); break;
    }
}

extern "C" void kernel_launch(void* const* d_in, const int* in_sizes, int n_in,
                              void* d_out, int out_size, void* d_ws, size_t ws_size,
                              hipStream_t stream)
{
    const float* x = (const float*)d_in[0];
    float* out = (float*)d_out;

    // Output layout: (lo3, hi1, hi2, hi3) concatenated flat
    float* lo3 = out;
    float* hi1 = out + (size_t)ROWS * O3;
    float* hi2 = hi1 + (size_t)ROWS * O1;
    float* hi3 = hi2 + (size_t)ROWS * O2;

    dwt_fused_kernel<<<dim3(NBLK, ROWS), dim3(NTHR), 0, stream>>>(
        x, lo3, hi1, hi2, hi3);
}